// Round 7
// baseline (193.666 us; speedup 1.0000x reference)
//
#include <hip/hip_runtime.h>
#include <math.h>

#define BOX   256
#define NPTS  50000
#define LATD  10
#define NEUR  32
#define NLAY  3
#define BATCH 16

#define MTPB  256
#define MBLKX ((NPTS + MTPB - 1)/MTPB)     // 196 blocks/image, 1 pt/thread

#define PTPB  256
#define PBLKX ((NPTS + PTPB - 1)/PTPB)     // 196

#define CELLS_X 64                          // 4x4-px cells
#define CELLS   (CELLS_X*CELLS_X)           // 4096
#define PREF_STRIDE 4104
#define CHUNK   128                         // worst-case nw = 4096+391 <= WCAP
#define WCAP    4608

// gather grid: 128 blocks/image * 4 waves = 512 waves/image (8192 total = chip capacity)
#define GBLK    128

#define IMG_ELEMS (BATCH*BOX*BOX)
#define OFF_IMG2  (IMG_ELEMS)
#define OFF_PROJ  (2*IMG_ELEMS)
#define OFF_POS   (OFF_PROJ + BATCH*NPTS*2)
#define OFF_RES   (OFF_POS  + BATCH*NPTS*3)

// ws ints: counts[16*4096] | n_work[16] | prefix[16*4104] | work[16*4608] | aux[16*50000]
// then (16B aligned): recs float4[16*50000]   -> ~16.8 MB total
// counts[] is dead after scan_cells; gather reuses counts[b*64] as its work cursor.
#define WS_COUNTS 0
#define WS_NWORK  (BATCH*CELLS)
#define WS_PREFIX (WS_NWORK + BATCH)
#define WS_WORK   (WS_PREFIX + BATCH*PREF_STRIDE)
#define WS_AUX    (WS_WORK + BATCH*WCAP)
#define WS_INTS   (WS_AUX + BATCH*NPTS)

// LDS h-tile row stride in HALFS: 32 cols + pad to 40 (80 B rows, 16B-aligned)
#define HSTRH 40

typedef _Float16 f16x8 __attribute__((ext_vector_type(8)));
typedef _Float16 f16x4 __attribute__((ext_vector_type(4)));
typedef float    f32x4 __attribute__((ext_vector_type(4)));

// raw v_exp_f32 (inputs bounded; skip OCML range-fixup code)
#if __has_builtin(__builtin_amdgcn_exp2f)
#define EXP2R(x) __builtin_amdgcn_exp2f(x)
#else
#define EXP2R(x) exp2f(x)
#endif

__device__ __forceinline__ float fast_tanh(float x) {
    return 1.0f - 2.0f / (__expf(2.0f * x) + 1.0f);
}

// ---- kernel A: fused MLP. lin0 + lin1a/b in VALU; 3 deform layers via
//      mfma_f32_16x16x32_f16 (A row=lane&15 k0=rq*8 via single ds_read_b128,
//      B col=lane&15 preloaded in VGPRs, D: col=lane&15 row=4rq+reg [m89]).
//      fp16 LDS tile (20.6 KB/block -> 7 blocks/CU vs 4 with fp32 tile);
//      fp32 residual/bias/acc in registers. Then histogram + base claim.
__global__ __launch_bounds__(MTPB) void mlp_bin(
    const float* __restrict__ z, const float* __restrict__ r,
    const float* __restrict__ pos_param, const float* __restrict__ amp,
    const float* __restrict__ lin0_w, const float* __restrict__ deform_w,
    const float* __restrict__ deform_b, const float* __restrict__ lin1a_w,
    const float* __restrict__ lin1b_w, const float* __restrict__ linamp_w,
    const float* __restrict__ linamp_b, const int* __restrict__ dflag,
    float* __restrict__ out, int* __restrict__ counts, int* __restrict__ aux)
{
    // raw LDS: 4 wave-private fp16 tiles [64][HSTRH] (20480 B) + zpart (128 B).
    // s_cnt (4096 ints = 16384 B) aliases tiles; used only after tile reads end.
    __shared__ __align__(16) unsigned char s_raw[4*64*HSTRH*2 + NEUR*4];
    _Float16* s_h   = (_Float16*)s_raw;
    float*    s_z   = (float*)(s_raw + 4*64*HSTRH*2);
    int*      s_cnt = (int*)s_raw;

    const int b     = blockIdx.y;
    const int tid   = threadIdx.x;
    const int wave  = tid >> 6;
    const int lane  = tid & 63;
    const int cfrag = lane & 15;           // A row / B col / D col
    const int rq    = lane >> 4;
    const int k0    = rq * 8;              // fragment K offset
    _Float16* __restrict__ s_hw = s_h + wave*64*HSTRH;

    if (tid < NEUR) {
        float acc = 0.f;
        #pragma unroll
        for (int j = 0; j < LATD-1; j++)
            acc = fmaf(lin0_w[tid*12 + 3 + j], z[b*LATD + j], acc);
        s_z[tid] = acc;
    }
    __syncthreads();

    const int n  = blockIdx.x*MTPB + tid;
    const bool v0 = (n < NPTS);
    const int m0 = v0 ? n : (NPTS-1);
    const int dd = *dflag;

    const float p0w = pos_param[m0*3+0], p1w = pos_param[m0*3+1], p2w = pos_param[m0*3+2];

    float res0 = 0.f, res1 = 0.f, res2 = 0.f;

    if (dd > 0) {
        // ---- preload deform weights as fp16 B-fragments + biases ----
        f16x8 bfrag[NLAY][2];
        float bias_c[NLAY][2];
        #pragma unroll
        for (int l = 0; l < NLAY; ++l) {
            #pragma unroll
            for (int nt = 0; nt < 2; ++nt) {
                const int c = cfrag + 16*nt;
                const float* wp = deform_w + l*NEUR*NEUR + c*NEUR + k0;
                const f32x4 w0 = *(const f32x4*)wp;
                const f32x4 w1 = *(const f32x4*)(wp + 4);
                f16x8 bv;
                bv[0]=(_Float16)w0[0]; bv[1]=(_Float16)w0[1];
                bv[2]=(_Float16)w0[2]; bv[3]=(_Float16)w0[3];
                bv[4]=(_Float16)w1[0]; bv[5]=(_Float16)w1[1];
                bv[6]=(_Float16)w1[2]; bv[7]=(_Float16)w1[3];
                bfrag[l][nt]  = bv;
                bias_c[l][nt] = deform_b[l*NEUR + c];
            }
        }

        // ---- lin0 in VALU: thread writes its own fp16 tile row (8 x b64) ----
        #pragma unroll
        for (int o4 = 0; o4 < 8; ++o4) {
            f16x4 h4;
            #pragma unroll
            for (int jj = 0; jj < 4; ++jj) {
                const int o = o4*4 + jj;
                h4[jj] = (_Float16)fmaf(lin0_w[o*12+0], p0w,
                                   fmaf(lin0_w[o*12+1], p1w,
                                   fmaf(lin0_w[o*12+2], p2w, s_z[o])));
            }
            *(f16x4*)&s_hw[lane*HSTRH + o4*4] = h4;   // 8B store, aligned
        }
        __syncthreads();

        // ---- one-time C-layout residual read of lin0 output (fp16 -> fp32 regs) ----
        float rs0[4][4], rs1[4][4];
        #pragma unroll
        for (int mt = 0; mt < 4; ++mt) {
            #pragma unroll
            for (int rr = 0; rr < 4; ++rr) {
                const int row = 16*mt + 4*rq + rr;
                rs0[mt][rr] = (float)s_hw[row*HSTRH + cfrag];
                rs1[mt][rr] = (float)s_hw[row*HSTRH + cfrag + 16];
            }
        }

        // ---- 3 residual relu layers via MFMA; residual stays in regs ----
        const f32x4 zc = {0.f, 0.f, 0.f, 0.f};
        #pragma unroll
        for (int l = 0; l < NLAY; ++l) {
            f16x8 af[4];
            #pragma unroll
            for (int mt = 0; mt < 4; ++mt)
                af[mt] = *(const f16x8*)&s_hw[(16*mt + cfrag)*HSTRH + k0]; // 16B, aligned
            f32x4 ac0[4], ac1[4];
            #pragma unroll
            for (int mt = 0; mt < 4; ++mt) {
                ac0[mt] = __builtin_amdgcn_mfma_f32_16x16x32_f16(af[mt], bfrag[l][0], zc, 0, 0, 0);
                ac1[mt] = __builtin_amdgcn_mfma_f32_16x16x32_f16(af[mt], bfrag[l][1], zc, 0, 0, 0);
            }
            __syncthreads();               // all tile reads done before overwrite
            const float b0l = bias_c[l][0], b1l = bias_c[l][1];
            #pragma unroll
            for (int mt = 0; mt < 4; ++mt) {
                #pragma unroll
                for (int rr = 0; rr < 4; ++rr) {
                    const int row = 16*mt + 4*rq + rr;
                    const float h0n = fmaxf(ac0[mt][rr] + b0l, 0.f) + rs0[mt][rr];
                    const float h1n = fmaxf(ac1[mt][rr] + b1l, 0.f) + rs1[mt][rr];
                    rs0[mt][rr] = h0n;
                    rs1[mt][rr] = h1n;
                    s_hw[row*HSTRH + cfrag]      = (_Float16)h0n;
                    s_hw[row*HSTRH + cfrag + 16] = (_Float16)h1n;
                }
            }
            __syncthreads();               // writes visible before next layer reads
        }

        // ---- lin1a + tanh + lin1b in VALU (thread reads its own fp16 row) ----
        float t0 = 0.f, t1 = 0.f, t2 = 0.f;
        #pragma unroll
        for (int ch = 0; ch < 4; ++ch) {
            const f16x8 hv = *(const f16x8*)&s_hw[lane*HSTRH + ch*8];
            #pragma unroll
            for (int jj = 0; jj < 8; ++jj) {
                const int j = ch*8 + jj;
                const float hf = (float)hv[jj];
                t0 = fmaf(lin1a_w[0*NEUR + j], hf, t0);
                t1 = fmaf(lin1a_w[1*NEUR + j], hf, t1);
                t2 = fmaf(lin1a_w[2*NEUR + j], hf, t2);
            }
        }
        t0 = fast_tanh(t0); t1 = fast_tanh(t1); t2 = fast_tanh(t2);
        res0 = fmaf(t0, lin1b_w[0], fmaf(t1, lin1b_w[1], t2*lin1b_w[2]));
        res1 = fmaf(t0, lin1b_w[3], fmaf(t1, lin1b_w[4], t2*lin1b_w[5]));
        res2 = fmaf(t0, lin1b_w[6], fmaf(t1, lin1b_w[7], t2*lin1b_w[8]));
    }

    // ---- epilogue: project, write outputs, bin ----
    const float r00 = r[b*9+0], r01 = r[b*9+1];
    const float r10 = r[b*9+3], r11 = r[b*9+4];
    const float r20 = r[b*9+6], r21 = r[b*9+7];

    int cell = 0;
    if (v0) {
        const float pos0 = p0w + res0, pos1 = p1w + res1, pos2 = p2w + res2;
        const float pj0 = fmaf(pos0, r00, fmaf(pos1, r10, pos2*r20));
        const float pj1 = fmaf(pos0, r01, fmaf(pos1, r11, pos2*r21));
        const long long bn = (long long)b*NPTS + n;
        out[OFF_PROJ + bn*2 + 0] = pj0;  out[OFF_PROJ + bn*2 + 1] = pj1;
        out[OFF_POS  + bn*3 + 0] = pos0; out[OFF_POS  + bn*3 + 1] = pos1;
        out[OFF_POS  + bn*3 + 2] = pos2;
        out[OFF_RES  + bn*3 + 0] = res0; out[OFF_RES + bn*3 + 1] = res1;
        out[OFF_RES  + bn*3 + 2] = res2;
        const float px0 = (pj0 + 0.5f) * (float)(BOX-1);
        const float px1 = (pj1 + 0.5f) * (float)(BOX-1);
        const int c0 = (int)fminf(fmaxf(floorf(px0 + 0.5f), 0.f), 255.f);
        const int c1 = (int)fminf(fmaxf(floorf(px1 + 0.5f), 0.f), 255.f);
        cell = (c0>>2)*CELLS_X + (c1>>2);
    }

    __syncthreads();                       // all tile reads done -> reuse as s_cnt
    for (int i = tid; i < CELLS; i += MTPB) s_cnt[i] = 0;
    __syncthreads();
    int rank = 0;
    if (v0) rank = atomicAdd(&s_cnt[cell], 1);
    __syncthreads();
    // claim global bases: one atomic per non-empty cell per block; s_cnt becomes base
    for (int c = tid; c < CELLS; c += MTPB) {
        const int cnt = s_cnt[c];
        if (cnt > 0) s_cnt[c] = atomicAdd(&counts[b*CELLS + c], cnt);
    }
    __syncthreads();
    if (v0) aux[b*NPTS + n] = (cell << 16) | (s_cnt[cell] + rank);
}

// ------- kernel B: shuffle-scan of 4096 cells per image (2 barriers) + work build -------
__global__ __launch_bounds__(1024) void scan_cells(
    const int* __restrict__ counts, int* __restrict__ prefix,
    int* __restrict__ n_work, int* __restrict__ work)
{
    __shared__ int wsum[16];
    __shared__ int s_nw;
    const int img = blockIdx.x, t = threadIdx.x;
    const int lane = t & 63, wid = t >> 6;
    if (t == 0) s_nw = 0;
    const int4 v = ((const int4*)(counts + img*CELLS))[t];
    const int s3 = v.x + v.y + v.z + v.w;

    // wave-level inclusive scan of per-thread sums
    int sc = s3;
    #pragma unroll
    for (int off = 1; off < 64; off <<= 1) {
        const int u = __shfl_up(sc, off, 64);
        if (lane >= off) sc += u;
    }
    if (lane == 63) wsum[wid] = sc;
    __syncthreads();
    if (wid == 0) {
        int ws = (lane < 16) ? wsum[lane] : 0;
        #pragma unroll
        for (int off = 1; off < 16; off <<= 1) {
            const int u = __shfl_up(ws, off, 64);
            if (lane >= off) ws += u;
        }
        if (lane < 16) wsum[lane] = ws;    // inclusive wave totals
    }
    __syncthreads();
    const int woff = (wid > 0) ? wsum[wid-1] : 0;
    const int incl = sc + woff;
    const int base = incl - s3;
    ((int4*)(prefix + img*PREF_STRIDE))[t] =
        make_int4(base, base+v.x, base+v.x+v.y, base+v.x+v.y+v.z);
    if (t == 1023) prefix[img*PREF_STRIDE + CELLS] = incl;

    // build_work: work item = (cell << 9) | chunk_idx  (chunk_idx < 512, CHUNK=128)
    const int cnts[4] = { v.x, v.y, v.z, v.w };
    #pragma unroll
    for (int i = 0; i < 4; i++) {
        const int cnt = cnts[i];
        if (cnt > 0) {
            const int c = 4*t + i;
            const int nch = (cnt + CHUNK - 1)/CHUNK;
            const int wb = atomicAdd(&s_nw, nch);
            for (int k = 0; k < nch; k++) work[img*WCAP + wb + k] = (c << 9) | k;
        }
    }
    __syncthreads();
    if (t == 0) n_work[img] = s_nw;
}

// ------- kernel C: place records at final cell-sorted positions; zero gather cursor -------
__global__ __launch_bounds__(PTPB) void place(
    const float* __restrict__ z, const float* __restrict__ amp,
    const float* __restrict__ linamp_w, const float* __restrict__ linamp_b,
    const float* __restrict__ out, const int* __restrict__ prefix,
    const int* __restrict__ aux, float4* __restrict__ recs, int* __restrict__ cursors)
{
    const int b = blockIdx.y;
    if (blockIdx.x == 0 && threadIdx.x == 0) cursors[b*64] = 0;  // gather work cursor
    const int n = blockIdx.x*PTPB + threadIdx.x;
    if (n >= NPTS) return;

    const long long bn = (long long)b*NPTS + n;
    const float pj0 = out[OFF_PROJ + bn*2 + 0];
    const float pj1 = out[OFF_PROJ + bn*2 + 1];
    const float lo = fmaf(z[b*LATD + LATD-1], linamp_w[n], linamp_b[n]);
    const float a  = amp[0] / (1.0f + __expf(-lo));
    const float px0 = (pj0 + 0.5f) * (float)(BOX-1);
    const float px1 = (pj1 + 0.5f) * (float)(BOX-1);

    const int av  = aux[b*NPTS + n];
    const int cell = av >> 16, wr = av & 0xFFFF;
    const int dst  = prefix[b*PREF_STRIDE + cell] + wr;
    // rec = (row, col, amp, center-row) ; center-row precomputed for gather
    recs[(long long)b*NPTS + dst] = make_float4(px0, px1, a, floorf(px0 + 0.5f));
}

// -------- kernel D: dynamic work-stealing; one wave per chunk grab;
//          fused radial exp2 (2 transcendentals/record), raw v_exp_f32 --------
__global__ __launch_bounds__(256) void gather_work(
    const float4* __restrict__ recs, const int* __restrict__ prefix,
    const int* __restrict__ n_work, const int* __restrict__ work,
    float* __restrict__ out, int* __restrict__ cursors)
{
    const int b    = blockIdx.y;
    const int lane = threadIdx.x & 63;
    const int nw   = n_work[b];
    int* __restrict__ cur = cursors + b*64;

    const int* __restrict__ P = prefix + b*PREF_STRIDE;
    const float4* __restrict__ R = recs + (long long)b*NPTS;
    float* __restrict__ img = out + (size_t)b*BOX*BOX;
    const float Kc  = -0.32059884f;                // -log2(e)/(2*sig^2)
    const float K8  = 8.0f  * Kc;
    const float K16 = 16.0f * Kc;
    const float C32 = 0.00081582472f;              // 2^(32*Kc)

    for (;;) {
        int grab;
        if (lane == 0) grab = atomicAdd(cur, 1);
        const int it = __shfl(grab, 0, 64);
        if (it >= nw) break;

        const int wd   = __builtin_amdgcn_readfirstlane(work[b*WCAP + it]);
        const int cell = wd >> 9, kch = wd & 511;
        const int s = P[cell] + kch*CHUNK;          // scalar (cell uniform)
        const int e = min(P[cell+1], s + CHUNK);

        const int cy = cell >> 6, cx = cell & 63;
        const int col = lane & 15, r0 = lane >> 4;
        const int gx  = 4*cx - 4 + col;
        const int gy0 = 4*cy - 4 + r0;
        const float xf  = (float)gx;
        const float y0f = (float)gy0;
        const float frc = (float)(r0 + 4*cy);       // fr0 + cy4, hoisted

        float a0 = 0.f, a1 = 0.f, a2 = 0.f;
        #pragma unroll 8
        for (int rr = s; rr < e; ++rr) {
            const float4 rc = R[rr];                // uniform addr -> s_load_dwordx4
            const float ry = rc.x, rx = rc.y, ra = rc.z, stf = rc.w;

            const float dx = xf - rx;
            const float dy = y0f - ry;
            // fused radial gaussian: g = ra * 2^((dx^2+dy^2)*Kc), x-window masked
            const float d2 = fmaf(dy, dy, dx*dx);
            float g = ra * EXP2R(d2 * Kc);
            g = (fabsf(dx) <= 4.5f) ? g : 0.f;      // == (dx>-4.5 && dx<=4.5): dx=-4.5 unreachable

            // row ladder: u = 2^(8*dy*Kc + 16*Kc); rows at dy, dy+4, dy+8
            // clamp 60: transparent for valid dy; keeps u^2 finite for outliers (no 0*inf)
            const float u  = EXP2R(fminf(fmaf(dy, K8, K16), 60.f));
            const float uu = (u * u) * C32;
            const float g0m = (frc >= stf) ? g  : 0.f;
            const float u2m = (frc <= stf) ? uu : 0.f;
            a0 += g0m;
            a1 = fmaf(g, u,   a1);
            a2 = fmaf(g, u2m, a2);
        }

        if (gx >= 0 && gx < BOX) {
            if (a0 != 0.f && gy0 >= 0)      atomicAdd(&img[ gy0     *BOX + gx], a0);
            if (a1 != 0.f)                  atomicAdd(&img[(gy0 + 4)*BOX + gx], a1);
            if (a2 != 0.f && gy0 + 8 < BOX) atomicAdd(&img[(gy0 + 8)*BOX + gx], a2);
        }
    }
}

__global__ __launch_bounds__(256) void copy_img(const float4* __restrict__ src,
                                                float4* __restrict__ dst, int n4)
{
    int i = blockIdx.x*blockDim.x + threadIdx.x;
    if (i < n4) dst[i] = src[i];
}

extern "C" void kernel_launch(void* const* d_in, const int* in_sizes, int n_in,
                              void* d_out, int out_size, void* d_ws, size_t ws_size,
                              hipStream_t stream)
{
    const float* z        = (const float*)d_in[0];
    const float* r        = (const float*)d_in[1];
    const float* posp     = (const float*)d_in[2];
    const float* amp      = (const float*)d_in[3];
    const float* lin0_w   = (const float*)d_in[4];
    const float* deform_w = (const float*)d_in[5];
    const float* deform_b = (const float*)d_in[6];
    const float* lin1a_w  = (const float*)d_in[7];
    const float* lin1b_w  = (const float*)d_in[8];
    const float* linamp_w = (const float*)d_in[9];
    const float* linamp_b = (const float*)d_in[10];
    const int*   dflag    = (const int*)d_in[11];
    float* out = (float*)d_out;

    int* ws_i    = (int*)d_ws;
    int* counts  = ws_i + WS_COUNTS;
    int* n_work  = ws_i + WS_NWORK;
    int* prefix  = ws_i + WS_PREFIX;
    int* work    = ws_i + WS_WORK;
    int* aux     = ws_i + WS_AUX;
    float4* recs = (float4*)((char*)d_ws + (size_t)WS_INTS*sizeof(int));

    hipMemsetAsync(counts, 0, (size_t)(BATCH*CELLS + BATCH)*sizeof(int), stream);
    hipMemsetAsync(out, 0, (size_t)IMG_ELEMS*sizeof(float), stream);

    dim3 gridM(MBLKX, BATCH);
    mlp_bin<<<gridM, MTPB, 0, stream>>>(z, r, posp, amp, lin0_w, deform_w, deform_b,
                                        lin1a_w, lin1b_w, linamp_w, linamp_b, dflag,
                                        out, counts, aux);

    scan_cells<<<BATCH, 1024, 0, stream>>>(counts, prefix, n_work, work);

    dim3 gridP(PBLKX, BATCH);
    place<<<gridP, PTPB, 0, stream>>>(z, amp, linamp_w, linamp_b, out, prefix, aux,
                                      recs, counts);

    dim3 gridG(GBLK, BATCH);
    gather_work<<<gridG, 256, 0, stream>>>(recs, prefix, n_work, work, out, counts);

    const int n4 = IMG_ELEMS/4;
    copy_img<<<(n4 + 255)/256, 256, 0, stream>>>((const float4*)out,
                                                 (float4*)(out + OFF_IMG2), n4);
}